// Round 1
// baseline (126.599 us; speedup 1.0000x reference)
//
#include <hip/hip_runtime.h>
#include <math.h>

#define NN 512
#define MM 31
#define TT 32            // M+1 tokens
#define EE 64            // INP = EMB = ATT
#define STR 68           // LDS row stride (floats): 16B-aligned, de-aliases banks
#define SELF_LOOP 200

__global__ __launch_bounds__(256) void transpool_kernel(
    const float* __restrict__ h,            // [N,64]
    const float* __restrict__ msg,          // [N,31,64]
    const int*   __restrict__ msg_type,     // [N,31]
    const int*   __restrict__ r_label_node, // [N]
    const int*   __restrict__ r_label_msg,  // [N,31]
    const float* __restrict__ W_self,       // [64,64]
    const float* __restrict__ Q,            // [201,64,64]
    const float* __restrict__ K,            // [201,64,64]
    const float* __restrict__ V,            // [201,64,64]
    const float* __restrict__ ffn_w,        // [64,64]
    const float* __restrict__ ffn_b,        // [64]
    float* __restrict__ out)                // [N,64]
{
    const int n   = blockIdx.x;
    const int tid = threadIdx.x;

    __shared__ float x_s[TT][STR];
    __shared__ float q_s[TT][STR];
    __shared__ float k_s[TT][STR];
    __shared__ float v_s[TT][STR];
    __shared__ float s_s[TT][TT + 1];
    __shared__ float att0[TT];
    __shared__ float pooled[EE];
    __shared__ int   qv_s[TT];
    __shared__ int   kx_s[TT];

    // ---- indices ----
    if (tid < TT) {
        qv_s[tid] = (tid == 0) ? r_label_node[n] : r_label_msg[n * MM + tid - 1];
        kx_s[tid] = (tid == 0) ? SELF_LOOP      : msg_type[n * MM + tid - 1];
    }

    // ---- msg -> x_s rows 1..31 (float4, coalesced) ----
    {
        const float4* msg4 = (const float4*)(msg + (size_t)n * MM * EE);
        for (int i4 = tid; i4 < MM * EE / 4; i4 += 256) {
            int m = i4 >> 4, c = i4 & 15;             // 16 float4 per 64-float row
            ((float4*)&x_s[1 + m][0])[c] = msg4[i4];
        }
    }

    // ---- curr = h[n] @ W_self -> x_s row 0 ----
    if (tid < EE) {
        float acc = 0.f;
        const float* hrow = h + n * EE;               // wave-uniform scalar loads
        for (int e = 0; e < EE; ++e)
            acc = fmaf(hrow[e], W_self[e * EE + tid], acc);
        x_s[0][tid] = acc;
    }
    __syncthreads();

    // ---- q/k/v projections: token m, output a. 16 lanes x float4 cover a row ----
    {
        const int a16 = tid & 15;                     // float4 column within row
        const int mo  = tid >> 4;                     // 0..15 token offset
        for (int mg = 0; mg < TT; mg += 16) {
            int m  = mg + mo;
            int rq = qv_s[m];
            int rk = kx_s[m];
            const float4* Qp = (const float4*)(Q + (size_t)rq * EE * EE) + a16;
            const float4* Kp = (const float4*)(K + (size_t)rk * EE * EE) + a16;
            const float4* Vp = (const float4*)(V + (size_t)rq * EE * EE) + a16;
            float4 qa = {0, 0, 0, 0}, ka = {0, 0, 0, 0}, va = {0, 0, 0, 0};
            for (int e = 0; e < EE; ++e) {
                float  xe = x_s[m][e];
                float4 qw = Qp[(size_t)e * 16];
                float4 kw = Kp[(size_t)e * 16];
                float4 vw = Vp[(size_t)e * 16];
                qa.x = fmaf(xe, qw.x, qa.x); qa.y = fmaf(xe, qw.y, qa.y);
                qa.z = fmaf(xe, qw.z, qa.z); qa.w = fmaf(xe, qw.w, qa.w);
                ka.x = fmaf(xe, kw.x, ka.x); ka.y = fmaf(xe, kw.y, ka.y);
                ka.z = fmaf(xe, kw.z, ka.z); ka.w = fmaf(xe, kw.w, ka.w);
                va.x = fmaf(xe, vw.x, va.x); va.y = fmaf(xe, vw.y, va.y);
                va.z = fmaf(xe, vw.z, va.z); va.w = fmaf(xe, vw.w, va.w);
            }
            ((float4*)&q_s[m][0])[a16] = qa;
            ((float4*)&k_s[m][0])[a16] = ka;
            ((float4*)&v_s[m][0])[a16] = va;
        }
    }
    __syncthreads();

    // ---- scores s[qi][ki] = dot(q[qi], k[ki]) / 8 ----
    {
        const int ki = tid & 31;
        for (int qi = tid >> 5; qi < TT; qi += 8) {
            const float4* qp = (const float4*)&q_s[qi][0];
            const float4* kp = (const float4*)&k_s[ki][0];
            float acc = 0.f;
            for (int e4 = 0; e4 < EE / 4; ++e4) {
                float4 a = qp[e4], b = kp[e4];
                acc += a.x * b.x + a.y * b.y + a.z * b.z + a.w * b.w;
            }
            s_s[qi][ki] = acc * 0.125f;
        }
    }
    __syncthreads();

    // ---- softmax over the QUERY axis (per column ki); only row 0 of att needed ----
    if (tid < TT) {
        float mx = -INFINITY;
        for (int qi = 0; qi < TT; ++qi) mx = fmaxf(mx, s_s[qi][tid]);
        float sum = 0.f;
        for (int qi = 0; qi < TT; ++qi) sum += __expf(s_s[qi][tid] - mx);
        att0[tid] = __expf(s_s[0][tid] - mx) / sum;
    }
    __syncthreads();

    // ---- pooled[a] = sum_k att0[k] * v[k][a] ----
    if (tid < EE) {
        float acc = 0.f;
        for (int ki = 0; ki < TT; ++ki)
            acc = fmaf(att0[ki], v_s[ki][tid], acc);
        pooled[tid] = acc;
    }
    __syncthreads();

    // ---- out = pooled @ ffn_w + ffn_b ----
    if (tid < EE) {
        float acc = ffn_b[tid];
        for (int a = 0; a < EE; ++a)
            acc = fmaf(pooled[a], ffn_w[a * EE + tid], acc);
        out[n * EE + tid] = acc;
    }
}

extern "C" void kernel_launch(void* const* d_in, const int* in_sizes, int n_in,
                              void* d_out, int out_size, void* d_ws, size_t ws_size,
                              hipStream_t stream) {
    const float* h            = (const float*)d_in[0];
    const float* msg          = (const float*)d_in[1];
    const int*   msg_type     = (const int*)  d_in[2];
    const int*   r_label_node = (const int*)  d_in[3];
    const int*   r_label_msg  = (const int*)  d_in[4];
    const float* W_self       = (const float*)d_in[5];
    const float* Q            = (const float*)d_in[6];
    const float* K            = (const float*)d_in[7];
    const float* V            = (const float*)d_in[8];
    const float* ffn_w        = (const float*)d_in[9];
    const float* ffn_b        = (const float*)d_in[10];
    float*       out          = (float*)d_out;

    transpool_kernel<<<NN, 256, 0, stream>>>(h, msg, msg_type, r_label_node,
                                             r_label_msg, W_self, Q, K, V,
                                             ffn_w, ffn_b, out);
}